// Round 10
// baseline (30.172 us; speedup 1.0000x reference)
//
#include <hip/hip_runtime.h>
#include <math.h>

#define HDIM 1024
#define NH 32
#define LLEN 4096
#define NT 512
#define NBLK 512   // 2 h per block
#define REP 10     // DIAGNOSTIC: repeat full body; output idempotent

typedef __attribute__((ext_vector_type(8))) short bf16x8;
typedef __attribute__((ext_vector_type(4))) float f32x4;

__device__ __forceinline__ unsigned int fbits(float x) { return __builtin_bit_cast(unsigned int, x); }
__device__ __forceinline__ float bitsf(unsigned int u) { return __builtin_bit_cast(float, u); }

struct Setup { float lr, li, re2, phi, plo; };

// z is an asm-opaque 0.0f: keeps all math inside the REP loop (defeats LICM)
__device__ __forceinline__ Setup make_setup(const float* __restrict__ C_ri,
                                            const float* __restrict__ log_dt,
                                            const float* __restrict__ log_A_real,
                                            const float* __restrict__ A_imag,
                                            int h, int n, float z) {
    const int hn = h * NH + n;
    const float LOG2E = 1.4426950408889634f;
    const float dt = exp2f((log_dt[h] + z) * LOG2E);
    const float Ar = -exp2f((log_A_real[hn] + z) * LOG2E);
    const float Ai = A_imag[hn] + z;
    const float dtAr = Ar * dt;
    const float dtAi = Ai * dt;

    Setup s;
    s.re2 = dtAr * 1.4426950408889634f;
    const double sd = (double)dtAi * 0.15915494309189535;
    const double fdd = sd - floor(sd);
    s.phi = (float)(floor(fdd * 4096.0 + 0.5) * (1.0 / 4096.0));
    s.plo = (float)(fdd - (double)s.phi);

    const float er = exp2f(s.re2);
    const float rv = (float)fdd;
    const float cs = __builtin_amdgcn_cosf(rv);
    const float sn = __builtin_amdgcn_sinf(rv);
    const float Er = er * cs - 1.0f;
    const float Ei = er * sn;
    const float cr = C_ri[2 * hn + 0];
    const float ci = C_ri[2 * hn + 1];
    const float nr = cr * Er - ci * Ei;
    const float ni = cr * Ei + ci * Er;
    const float inv = 1.0f / (Ar * Ar + Ai * Ai);
    s.lr = (nr * Ar + ni * Ai) * inv;
    s.li = (ni * Ar - nr * Ai) * inv;
    return s;
}

__device__ __forceinline__ void build_h(const Setup& s, int n, int r0,
                                        unsigned short (*T)[64][64]) {
    auto zpow = [&](float m, float& zr, float& zi) {
        const float x = s.phi * m;
        const float fr = x - floorf(x);
        float rev = fmaf(s.plo, m, fr);
        rev -= floorf(rev);
        const float ev = exp2f(s.re2 * m);
        zr = ev * __builtin_amdgcn_cosf(rev);
        zi = ev * __builtin_amdgcn_sinf(rev);
    };
    auto put = [&](int tab, int row, float vr, float vi) {
        const unsigned ur = fbits(vr), ui = fbits(vi);
        const unsigned hp = (ur >> 16) | (ui & 0xFFFF0000u);
        const float rl = vr - bitsf(ur & 0xFFFF0000u);
        const float il = vi - bitsf(ui & 0xFFFF0000u);
        const unsigned lp = (fbits(rl) >> 16) | (fbits(il) & 0xFFFF0000u);
        const int c = n ^ ((row & 7) << 2);
        ((unsigned*)T[tab][row])[c] = hp;
        ((unsigned*)T[tab + 1][row])[c] = lp;
    };

    {
        float zr, zi, sr, si;
        zpow((float)r0, zr, zi);
        zpow(16.0f, sr, si);
        int row = r0;
#pragma unroll
        for (int k = 0; k < 4; ++k) {
            put(0, row, zr, zi);
            const float t = zr * sr - zi * si;
            zi = zr * si + zi * sr;
            zr = t;
            row += 16;
        }
    }
    {
        float zr, zi, sr, si;
        zpow((float)(64 * r0), zr, zi);
        zpow(1024.0f, sr, si);
        float ur = s.lr * zr - s.li * zi;
        float ui = s.lr * zi + s.li * zr;
        int row = r0;
#pragma unroll
        for (int k = 0; k < 4; ++k) {
            put(2, row, ur + ur, -(ui + ui));
            const float t = ur * sr - ui * si;
            ui = ur * si + ui * sr;
            ur = t;
            row += 16;
        }
    }
}

__device__ __forceinline__ void gemm_store(const unsigned short (*T)[64][64],
                                           int tid, float* __restrict__ outh) {
    const int lane = tid & 63;
    const int wv = tid >> 6;
    const int li16 = lane & 15;
    const int lg = lane >> 4;
    const int arow = wv & 3;
    const int tc0 = (wv >> 2) * 2;

    f32x4 acc0 = (f32x4){0.f, 0.f, 0.f, 0.f};
    f32x4 acc1 = (f32x4){0.f, 0.f, 0.f, 0.f};

    const int rowA = 16 * arow + li16;
    const int rowB0 = 16 * tc0 + li16;
    const int rowB1 = rowB0 + 16;

#pragma unroll
    for (int st = 0; st < 6; ++st) {
        const int tabA = (st >= 4) ? 1 : 0;
        const int tabB = (st == 2 || st == 3) ? 3 : 2;
        const int j = 4 * (st & 1) + lg;
        const bf16x8 af = *(const bf16x8*)&T[tabA][rowA][8 * (j ^ (rowA & 7))];
        const bf16x8 b0 = *(const bf16x8*)&T[tabB][rowB0][8 * (j ^ (rowB0 & 7))];
        const bf16x8 b1 = *(const bf16x8*)&T[tabB][rowB1][8 * (j ^ (rowB1 & 7))];
        acc0 = __builtin_amdgcn_mfma_f32_16x16x32_bf16(af, b0, acc0, 0, 0, 0);
        acc1 = __builtin_amdgcn_mfma_f32_16x16x32_bf16(af, b1, acc1, 0, 0, 0);
    }

    const int rr = 16 * arow + 4 * lg;
    *(f32x4*)&outh[64 * (16 * tc0 + li16) + rr] = acc0;
    *(f32x4*)&outh[64 * (16 * tc0 + 16 + li16) + rr] = acc1;
}

__global__ __launch_bounds__(NT, 4) void s4d_kernel(
    const float* __restrict__ C_ri,
    const float* __restrict__ log_dt,
    const float* __restrict__ log_A_real,
    const float* __restrict__ A_imag,
    float* __restrict__ out)
{
    __shared__ unsigned short sT[2][4][64][64];

    const int tid = threadIdx.x;
    const int n = tid & 31;
    const int r0 = tid >> 5;
    const int h0 = blockIdx.x;
    const int h1 = blockIdx.x + NBLK;

    float z;
    asm volatile("v_mov_b32 %0, 0" : "=v"(z));   // opaque 0.0f

#pragma clang loop unroll(disable)
    for (int rep = 0; rep < REP; ++rep) {
        const Setup s0 = make_setup(C_ri, log_dt, log_A_real, A_imag, h0, n, z);
        const Setup s1 = make_setup(C_ri, log_dt, log_A_real, A_imag, h1, n, z);

        build_h(s0, n, r0, sT[0]);
        __syncthreads();
        gemm_store(sT[0], tid, out + h0 * LLEN);
        build_h(s1, n, r0, sT[1]);
        __syncthreads();
        gemm_store(sT[1], tid, out + h1 * LLEN);
        __syncthreads();
        asm volatile("" ::: "memory");
    }
}

extern "C" void kernel_launch(void* const* d_in, const int* in_sizes, int n_in,
                              void* d_out, int out_size, void* d_ws, size_t ws_size,
                              hipStream_t stream) {
    const float* C_ri       = (const float*)d_in[0];
    const float* log_dt     = (const float*)d_in[1];
    const float* log_A_real = (const float*)d_in[2];
    const float* A_imag     = (const float*)d_in[3];
    float* out = (float*)d_out;

    s4d_kernel<<<dim3(NBLK), dim3(NT), 0, stream>>>(C_ri, log_dt, log_A_real, A_imag, out);
}

// Round 11
// 12.742 us; speedup vs baseline: 2.3680x; 2.3680x over previous
//
#include <hip/hip_runtime.h>
#include <math.h>

#define HDIM 1024
#define NH 32
#define LLEN 4096
#define NT 512
#define NBLK 512   // 2 h per block

typedef __attribute__((ext_vector_type(8))) short bf16x8;
typedef __attribute__((ext_vector_type(4))) float f32x4;

__device__ __forceinline__ unsigned int fbits(float x) { return __builtin_bit_cast(unsigned int, x); }
__device__ __forceinline__ float bitsf(unsigned int u) { return __builtin_bit_cast(float, u); }

struct Setup { float lr, li, re2, phi, plo; };

__device__ __forceinline__ Setup make_setup(const float* __restrict__ C_ri,
                                            const float* __restrict__ log_dt,
                                            const float* __restrict__ log_A_real,
                                            const float* __restrict__ A_imag,
                                            int h, int n) {
    const int hn = h * NH + n;
    const float LOG2E = 1.4426950408889634f;
    const float dt = exp2f(log_dt[h] * LOG2E);
    const float Ar = -exp2f(log_A_real[hn] * LOG2E);
    const float Ai = A_imag[hn];
    const float dtAr = Ar * dt;
    const float dtAi = Ai * dt;

    Setup s;
    s.re2 = dtAr * LOG2E;                          // decay, log2 units per l
    const double sd = (double)dtAi * 0.15915494309189535;
    const double fdd = sd - floor(sd);             // exact fract(dtAi/2pi)
    s.phi = (float)(floor(fdd * 4096.0 + 0.5) * (1.0 / 4096.0));
    s.plo = (float)(fdd - (double)s.phi);          // exact hi/lo split (rev/l)

    // lhs = C*(exp(dtA)-1)/A   (x2/-2 folded at B build)
    const float er = exp2f(s.re2);
    const float rv = (float)fdd;
    const float cs = __builtin_amdgcn_cosf(rv);
    const float sn = __builtin_amdgcn_sinf(rv);
    const float Er = er * cs - 1.0f;
    const float Ei = er * sn;
    const float cr = C_ri[2 * hn + 0];
    const float ci = C_ri[2 * hn + 1];
    const float nr = cr * Er - ci * Ei;
    const float ni = cr * Ei + ci * Er;
    const float inv = 1.0f / (Ar * Ar + Ai * Ai);
    s.lr = (nr * Ar + ni * Ai) * inv;
    s.li = (ni * Ar - nr * Ai) * inv;
    return s;
}

// tables T[tab][64][64] bf16, tab: 0=Ah 1=Al 2=Bh 3=Bl
// swizzle: 16B granule g at row -> g ^ (row&7)  (dword col c -> c ^ ((row&7)<<2))
__device__ __forceinline__ void build_h(const Setup& s, int n, int r0,
                                        unsigned short (*T)[64][64]) {
    auto zpow = [&](float m, float& zr, float& zi) {
        const float x = s.phi * m;                 // exact: 12-bit phi x int
        const float fr = x - floorf(x);
        float rev = fmaf(s.plo, m, fr);
        rev -= floorf(rev);                        // [0,1) revolutions
        const float ev = exp2f(s.re2 * m);
        zr = ev * __builtin_amdgcn_cosf(rev);
        zi = ev * __builtin_amdgcn_sinf(rev);
    };
    auto put = [&](int tab, int row, float vr, float vi) {
        const unsigned ur = fbits(vr), ui = fbits(vi);
        const unsigned hp = (ur >> 16) | (ui & 0xFFFF0000u);
        const float rl = vr - bitsf(ur & 0xFFFF0000u);
        const float il = vi - bitsf(ui & 0xFFFF0000u);
        const unsigned lp = (fbits(rl) >> 16) | (fbits(il) & 0xFFFF0000u);
        const int c = n ^ ((row & 7) << 2);
        ((unsigned*)T[tab][row])[c] = hp;
        ((unsigned*)T[tab + 1][row])[c] = lp;
    };

    // A-table: z^row, rows r0+16k, via chain z^{r0} * (z^16)^k
    {
        float zr, zi, sr, si;
        zpow((float)r0, zr, zi);
        zpow(16.0f, sr, si);
        int row = r0;
#pragma unroll
        for (int k = 0; k < 4; ++k) {
            put(0, row, zr, zi);
            const float t = zr * sr - zi * si;
            zi = zr * si + zi * sr;
            zr = t;
            row += 16;
        }
    }
    // B-table: (2Re,-2Im)(lhs*z^{64 row}), via chain (lhs*z^{64 r0}) * (z^1024)^k
    {
        float zr, zi, sr, si;
        zpow((float)(64 * r0), zr, zi);
        zpow(1024.0f, sr, si);
        float ur = s.lr * zr - s.li * zi;
        float ui = s.lr * zi + s.li * zr;
        int row = r0;
#pragma unroll
        for (int k = 0; k < 4; ++k) {
            put(2, row, ur + ur, -(ui + ui));
            const float t = ur * sr - ui * si;
            ui = ur * si + ui * sr;
            ur = t;
            row += 16;
        }
    }
}

__device__ __forceinline__ void gemm_store(const unsigned short (*T)[64][64],
                                           int tid, float* __restrict__ outh) {
    const int lane = tid & 63;
    const int wv = tid >> 6;
    const int li16 = lane & 15;
    const int lg = lane >> 4;
    const int arow = wv & 3;
    const int tc0 = (wv >> 2) * 2;

    f32x4 acc0 = (f32x4){0.f, 0.f, 0.f, 0.f};
    f32x4 acc1 = (f32x4){0.f, 0.f, 0.f, 0.f};

    const int rowA = 16 * arow + li16;
    const int rowB0 = 16 * tc0 + li16;
    const int rowB1 = rowB0 + 16;

    // st=0,1: Ah*Bh ; st=2,3: Ah*Bl ; st=4,5: Al*Bh  (k-half = st&1)
#pragma unroll
    for (int st = 0; st < 6; ++st) {
        const int tabA = (st >= 4) ? 1 : 0;
        const int tabB = (st == 2 || st == 3) ? 3 : 2;
        const int j = 4 * (st & 1) + lg;           // 16B granule index
        const bf16x8 af = *(const bf16x8*)&T[tabA][rowA][8 * (j ^ (rowA & 7))];
        const bf16x8 b0 = *(const bf16x8*)&T[tabB][rowB0][8 * (j ^ (rowB0 & 7))];
        const bf16x8 b1 = *(const bf16x8*)&T[tabB][rowB1][8 * (j ^ (rowB1 & 7))];
        acc0 = __builtin_amdgcn_mfma_f32_16x16x32_bf16(af, b0, acc0, 0, 0, 0);
        acc1 = __builtin_amdgcn_mfma_f32_16x16x32_bf16(af, b1, acc1, 0, 0, 0);
    }

    // l = 64q + r; r = 16*arow+4*lg+reg contiguous -> float4 stores
    const int rr = 16 * arow + 4 * lg;
    *(f32x4*)&outh[64 * (16 * tc0 + li16) + rr] = acc0;
    *(f32x4*)&outh[64 * (16 * tc0 + 16 + li16) + rr] = acc1;
}

__global__ __launch_bounds__(NT, 4) void s4d_kernel(
    const float* __restrict__ C_ri,
    const float* __restrict__ log_dt,
    const float* __restrict__ log_A_real,
    const float* __restrict__ A_imag,
    float* __restrict__ out)
{
    __shared__ unsigned short sT[2][4][64][64];    // 64 KB: double-buffered

    const int tid = threadIdx.x;
    const int n = tid & 31;
    const int r0 = tid >> 5;
    const int h0 = blockIdx.x;
    const int h1 = blockIdx.x + NBLK;

    // both setups up front: input loads + f64 chains overlap
    const Setup s0 = make_setup(C_ri, log_dt, log_A_real, A_imag, h0, n);
    const Setup s1 = make_setup(C_ri, log_dt, log_A_real, A_imag, h1, n);

    build_h(s0, n, r0, sT[0]);
    __syncthreads();
    gemm_store(sT[0], tid, out + h0 * LLEN);       // reads buf0, stores flow
    build_h(s1, n, r0, sT[1]);                     // writes buf1 (no conflict)
    __syncthreads();
    gemm_store(sT[1], tid, out + h1 * LLEN);
}

extern "C" void kernel_launch(void* const* d_in, const int* in_sizes, int n_in,
                              void* d_out, int out_size, void* d_ws, size_t ws_size,
                              hipStream_t stream) {
    const float* C_ri       = (const float*)d_in[0];
    const float* log_dt     = (const float*)d_in[1];
    const float* log_A_real = (const float*)d_in[2];
    const float* A_imag     = (const float*)d_in[3];
    float* out = (float*)d_out;

    s4d_kernel<<<dim3(NBLK), dim3(NT), 0, stream>>>(C_ri, log_dt, log_A_real, A_imag, out);
}